// Round 1
// baseline (514.445 us; speedup 1.0000x reference)
//
#include <hip/hip_runtime.h>
#include <math.h>

typedef __bf16 bf16_t;
typedef bf16_t bf16x8 __attribute__((ext_vector_type(8)));
typedef float f32x4 __attribute__((ext_vector_type(4)));

#define HIDDEN 2048
#define SEQ 2048
#define BATCH 2
#define NHEADS 16
#define HDIM 128
#define MTOT (BATCH*SEQ)
#define SCALE 0.088388347648318447f

// ---- async global->LDS (wave-uniform LDS base + lane*16, per m97) ----
typedef __attribute__((address_space(1))) const void gvoid_t;
typedef __attribute__((address_space(3))) void svoid_t;
__device__ __forceinline__ void async_copy16(const bf16_t* g, bf16_t* l) {
  __builtin_amdgcn_global_load_lds((gvoid_t*)g, (svoid_t*)l, 16, 0, 0);
}

// ---- fp32 -> bf16 cast, float4 vectorized ----
__global__ void cvt_f32_bf16(const float* __restrict__ in, bf16_t* __restrict__ out, int n4) {
  int i = blockIdx.x * 256 + threadIdx.x;
  if (i >= n4) return;
  float4 v = reinterpret_cast<const float4*>(in)[i];
  union { bf16_t h[4]; uint2 u; } t;
  t.h[0] = (bf16_t)v.x; t.h[1] = (bf16_t)v.y; t.h[2] = (bf16_t)v.z; t.h[3] = (bf16_t)v.w;
  reinterpret_cast<uint2*>(out)[i] = t.u;
}

__global__ void pack_bias2(const float* __restrict__ a, const float* __restrict__ b2,
                           float* __restrict__ out) {
  int i = blockIdx.x * 256 + threadIdx.x;      // 0..4095
  out[i] = (i < HIDDEN) ? a[i] : b2[i - HIDDEN];
}

// ---- GEMM: Y[i][j] = sum_k A[i][k]*Bt[j][k] + bias  (both operands K-major) ----
// 128x128 tile, BK=32, 4 waves in 2x2, 16x16x32 bf16 MFMA. m97 structure.
template<bool OUT_BF16, bool ROW_BIAS>
__global__ __launch_bounds__(256, 2)
void gemm_bt(const bf16_t* __restrict__ A, const bf16_t* __restrict__ Bt,
             const float* __restrict__ bias, void* __restrict__ Yv,
             int M, int N, int K, int ldY) {
  __shared__ __align__(16) bf16_t As[128 * 32];
  __shared__ __align__(16) bf16_t Bs[128 * 32];
  const int tid  = threadIdx.x;
  const int lane = tid & 63;
  const int wv   = tid >> 6;
  const int wr   = wv >> 1, wc = wv & 1;
  const int lr   = lane & 15, quad = lane >> 4;
  const int n0   = blockIdx.x * 128;
  const int m0   = blockIdx.y * 128;

  f32x4 acc[4][4] = {};

  const int srow = wv * 16 + (lane >> 2);      // 0..63
  const int scol = (lane & 3) * 8;
  const bf16_t* gA = A  + (size_t)(m0 + srow) * K + scol;
  const bf16_t* gB = Bt + (size_t)(n0 + srow) * K + scol;
  bf16_t* lA = &As[wv * 16 * 32];              // wave-uniform LDS base
  bf16_t* lB = &Bs[wv * 16 * 32];
  const size_t step64 = (size_t)64 * K;

  for (int kt = 0; kt < K; kt += 32) {
    __syncthreads();                           // prior ds_reads complete
    async_copy16(gA,          lA);
    async_copy16(gA + step64, lA + 64 * 32);
    async_copy16(gB,          lB);
    async_copy16(gB + step64, lB + 64 * 32);
    gA += 32; gB += 32;
    __syncthreads();                           // drains vmcnt -> tiles visible
    bf16x8 af[4], bfr[4];
#pragma unroll
    for (int mi = 0; mi < 4; ++mi)
      af[mi] = *(const bf16x8*)&As[(wr * 64 + mi * 16 + lr) * 32 + quad * 8];
#pragma unroll
    for (int ni = 0; ni < 4; ++ni)
      bfr[ni] = *(const bf16x8*)&Bs[(wc * 64 + ni * 16 + lr) * 32 + quad * 8];
#pragma unroll
    for (int mi = 0; mi < 4; ++mi)
#pragma unroll
      for (int ni = 0; ni < 4; ++ni)
        acc[mi][ni] = __builtin_amdgcn_mfma_f32_16x16x32_bf16(af[mi], bfr[ni], acc[mi][ni], 0, 0, 0);
  }

  float bcol[4];
  if (!ROW_BIAS) {
#pragma unroll
    for (int ni = 0; ni < 4; ++ni) bcol[ni] = bias[n0 + wc * 64 + ni * 16 + lr];
  }
#pragma unroll
  for (int mi = 0; mi < 4; ++mi) {
#pragma unroll
    for (int r = 0; r < 4; ++r) {
      int row = m0 + wr * 64 + mi * 16 + quad * 4 + r;
      float brow = ROW_BIAS ? bias[row] : 0.0f;
      size_t base = (size_t)row * ldY + n0 + wc * 64;
#pragma unroll
      for (int ni = 0; ni < 4; ++ni) {
        float y = acc[mi][ni][r] + (ROW_BIAS ? brow : bcol[ni]);
        int col = ni * 16 + lr;
        if (OUT_BF16) ((bf16_t*)Yv)[base + col] = (bf16_t)y;
        else          ((float*)Yv)[base + col]  = y;
      }
    }
  }
}

// ---- Flash attention: QK packed [4096][4096] (Q cols 0..2047, K cols 2048..4095),
// ---- Vt [2048][4096] (row = h*128+d, col = b*2048+s). Out ctx bf16 [4096][2048].
#define BQ 128
#define BKV 64
#define QSTR 136
#define KSTR 136
#define VSTR 72
#define PSTR 72
#define LDQK 4096

__global__ __launch_bounds__(256, 2)
void attn_kernel(const bf16_t* __restrict__ QK, const bf16_t* __restrict__ Vt,
                 const float* __restrict__ mask, bf16_t* __restrict__ O) {
  __shared__ __align__(16) bf16_t Qs[BQ * QSTR];    // 34816 B; reused as P after Q frags load
  __shared__ __align__(16) bf16_t Ks[BKV * KSTR];   // 17408 B
  __shared__ __align__(16) bf16_t Vs[HDIM * VSTR];  // 18432 B  (total 69 KB -> 2 blocks/CU)
  bf16_t* Ps = Qs;

  const int tid  = threadIdx.x;
  const int lane = tid & 63;
  const int wv   = tid >> 6;                        // wave owns q rows [wv*32, wv*32+32)
  const int lr   = lane & 15, quad = lane >> 4;
  const int q0   = blockIdx.x * BQ;
  const int bh   = blockIdx.y;
  const int b    = bh >> 4, h = bh & 15;

  const bf16_t* Qg = QK + (size_t)(b * SEQ + q0) * LDQK + h * HDIM;
  const bf16_t* Kg = QK + (size_t)(b * SEQ) * LDQK + HIDDEN + h * HDIM;
  const bf16_t* Vg = Vt + (size_t)(h * HDIM) * MTOT + b * SEQ;
  const float*  mb = mask + b * SEQ;

  // stage Q tile [128][128]
#pragma unroll
  for (int idx = tid; idx < BQ * 16; idx += 256) {
    int r = idx >> 4, c8 = idx & 15;
    uint4 u = *(const uint4*)(Qg + (size_t)r * LDQK + c8 * 8);
    *(uint4*)&Qs[r * QSTR + c8 * 8] = u;
  }
  __syncthreads();

  bf16x8 qf[2][4];
#pragma unroll
  for (int mi = 0; mi < 2; ++mi)
#pragma unroll
    for (int dk = 0; dk < 4; ++dk)
      qf[mi][dk] = *(const bf16x8*)&Qs[(wv * 32 + mi * 16 + lr) * QSTR + dk * 32 + quad * 8];

  float m_st[2][4], l_st[2][4];
#pragma unroll
  for (int mi = 0; mi < 2; ++mi)
#pragma unroll
    for (int r = 0; r < 4; ++r) { m_st[mi][r] = -1e30f; l_st[mi][r] = 0.0f; }
  f32x4 oacc[2][8] = {};

  for (int kt = 0; kt < SEQ; kt += BKV) {
    __syncthreads();   // prev tile consumed (also orders first P write after qf loads)
    // stage K tile [64][128]
#pragma unroll
    for (int idx = tid; idx < BKV * 16; idx += 256) {
      int r = idx >> 4, c8 = idx & 15;
      uint4 u = *(const uint4*)(Kg + (size_t)(kt + r) * LDQK + c8 * 8);
      *(uint4*)&Ks[r * KSTR + c8 * 8] = u;
    }
    // stage V^T tile [128 d][64 k] (already transposed in global -> vector writes)
#pragma unroll
    for (int idx = tid; idx < HDIM * 8; idx += 256) {
      int d = idx >> 3, c8 = idx & 7;
      uint4 u = *(const uint4*)(Vg + (size_t)d * MTOT + kt + c8 * 8);
      *(uint4*)&Vs[d * VSTR + c8 * 8] = u;
    }
    __syncthreads();

    // S = Q K^T  (per wave: [32 q][64 k])
    f32x4 sacc[2][4] = {};
#pragma unroll
    for (int dk = 0; dk < 4; ++dk) {
      bf16x8 kf[4];
#pragma unroll
      for (int ni = 0; ni < 4; ++ni)
        kf[ni] = *(const bf16x8*)&Ks[(ni * 16 + lr) * KSTR + dk * 32 + quad * 8];
#pragma unroll
      for (int mi = 0; mi < 2; ++mi)
#pragma unroll
        for (int ni = 0; ni < 4; ++ni)
          sacc[mi][ni] = __builtin_amdgcn_mfma_f32_16x16x32_bf16(qf[mi][dk], kf[ni], sacc[mi][ni], 0, 0, 0);
    }

    float mk[4];
#pragma unroll
    for (int ni = 0; ni < 4; ++ni) mk[ni] = mb[kt + ni * 16 + lr];

    // online softmax; C-layout row = quad*4+r, col = lr
#pragma unroll
    for (int mi = 0; mi < 2; ++mi) {
      float alpha[4];
#pragma unroll
      for (int r = 0; r < 4; ++r) {
        float x0 = sacc[mi][0][r] * SCALE + mk[0];
        float x1 = sacc[mi][1][r] * SCALE + mk[1];
        float x2 = sacc[mi][2][r] * SCALE + mk[2];
        float x3 = sacc[mi][3][r] * SCALE + mk[3];
        float mx = fmaxf(fmaxf(x0, x1), fmaxf(x2, x3));
        mx = fmaxf(mx, __shfl_xor(mx, 1));
        mx = fmaxf(mx, __shfl_xor(mx, 2));
        mx = fmaxf(mx, __shfl_xor(mx, 4));
        mx = fmaxf(mx, __shfl_xor(mx, 8));
        float mnew = fmaxf(m_st[mi][r], mx);
        alpha[r] = __expf(m_st[mi][r] - mnew);
        m_st[mi][r] = mnew;
        float p0 = __expf(x0 - mnew), p1 = __expf(x1 - mnew);
        float p2 = __expf(x2 - mnew), p3 = __expf(x3 - mnew);
        int prow = (wv * 32 + mi * 16 + quad * 4 + r) * PSTR;
        Ps[prow +  0 + lr] = (bf16_t)p0;
        Ps[prow + 16 + lr] = (bf16_t)p1;
        Ps[prow + 32 + lr] = (bf16_t)p2;
        Ps[prow + 48 + lr] = (bf16_t)p3;
        float s = p0 + p1 + p2 + p3;
        s += __shfl_xor(s, 1);
        s += __shfl_xor(s, 2);
        s += __shfl_xor(s, 4);
        s += __shfl_xor(s, 8);
        l_st[mi][r] = l_st[mi][r] * alpha[r] + s;
      }
#pragma unroll
      for (int di = 0; di < 8; ++di) {
        f32x4 o = oacc[mi][di];
        o[0] *= alpha[0]; o[1] *= alpha[1]; o[2] *= alpha[2]; o[3] *= alpha[3];
        oacc[mi][di] = o;
      }
    }
    __syncthreads();   // P visible (C-layout -> A-layout via LDS round trip)

    // O += P V   (per wave: [32 q][128 d])
#pragma unroll
    for (int ki = 0; ki < 2; ++ki) {
      bf16x8 pf[2];
#pragma unroll
      for (int mi = 0; mi < 2; ++mi)
        pf[mi] = *(const bf16x8*)&Ps[(wv * 32 + mi * 16 + lr) * PSTR + ki * 32 + quad * 8];
#pragma unroll
      for (int di = 0; di < 8; ++di) {
        bf16x8 vf = *(const bf16x8*)&Vs[(di * 16 + lr) * VSTR + ki * 32 + quad * 8];
#pragma unroll
        for (int mi = 0; mi < 2; ++mi)
          oacc[mi][di] = __builtin_amdgcn_mfma_f32_16x16x32_bf16(pf[mi], vf, oacc[mi][di], 0, 0, 0);
      }
    }
  }

  // epilogue: O /= l, write ctx bf16 [b*S+q][h*128+d]
  bf16_t* Ob = O + (size_t)(b * SEQ + q0) * HIDDEN + h * HDIM;
#pragma unroll
  for (int mi = 0; mi < 2; ++mi) {
#pragma unroll
    for (int r = 0; r < 4; ++r) {
      float inv = 1.0f / l_st[mi][r];
      size_t rowoff = (size_t)(wv * 32 + mi * 16 + quad * 4 + r) * HIDDEN;
#pragma unroll
      for (int di = 0; di < 8; ++di)
        Ob[rowoff + di * 16 + lr] = (bf16_t)(oacc[mi][di][r] * inv);
    }
  }
}

extern "C" void kernel_launch(void* const* d_in, const int* in_sizes, int n_in,
                              void* d_out, int out_size, void* d_ws, size_t ws_size,
                              hipStream_t stream) {
  const float* x   = (const float*)d_in[0];
  const float* msk = (const float*)d_in[1];
  const float* Wq  = (const float*)d_in[2];
  const float* bq  = (const float*)d_in[3];
  const float* Wk  = (const float*)d_in[4];
  const float* bk  = (const float*)d_in[5];
  const float* Wv  = (const float*)d_in[6];
  const float* bv  = (const float*)d_in[7];
  const float* Wo  = (const float*)d_in[8];
  const float* bo  = (const float*)d_in[9];
  float* out = (float*)d_out;

  // workspace layout (bf16 elems), ~101 MB total
  bf16_t* Xb   = (bf16_t*)d_ws;
  bf16_t* Wqkb = Xb   + (size_t)MTOT * HIDDEN;            // Wq|Wk stacked [4096][2048]
  bf16_t* Wvb  = Wqkb + (size_t)2 * HIDDEN * HIDDEN;
  bf16_t* Wob  = Wvb  + (size_t)HIDDEN * HIDDEN;
  bf16_t* QKo  = Wob  + (size_t)HIDDEN * HIDDEN;          // [4096][4096]
  bf16_t* Vto  = QKo  + (size_t)MTOT * 2 * HIDDEN;        // [2048][4096]
  float*  bqk  = (float*)(Vto + (size_t)HIDDEN * MTOT);   // [4096] fp32
  bf16_t* Cb   = Xb;  // ctx aliases Xb (Xb dead after Vt GEMM)

  const int n4x = MTOT * HIDDEN / 4;
  const int n4w = HIDDEN * HIDDEN / 4;
  cvt_f32_bf16<<<n4x / 256, 256, 0, stream>>>(x,  Xb, n4x);
  cvt_f32_bf16<<<n4w / 256, 256, 0, stream>>>(Wq, Wqkb, n4w);
  cvt_f32_bf16<<<n4w / 256, 256, 0, stream>>>(Wk, Wqkb + (size_t)HIDDEN * HIDDEN, n4w);
  cvt_f32_bf16<<<n4w / 256, 256, 0, stream>>>(Wv, Wvb, n4w);
  cvt_f32_bf16<<<n4w / 256, 256, 0, stream>>>(Wo, Wob, n4w);
  pack_bias2<<<2 * HIDDEN / 256, 256, 0, stream>>>(bq, bk, bqk);

  // QK projection: [4096,2048] x [4096,2048]^T -> [4096][4096]
  gemm_bt<true, false><<<dim3(32, 32), 256, 0, stream>>>(Xb, Wqkb, bqk, QKo,
                                                         MTOT, 2 * HIDDEN, HIDDEN, 2 * HIDDEN);
  // V^T projection (operands swapped): [2048,2048] x [4096,2048]^T -> [2048][4096], row bias
  gemm_bt<true, true><<<dim3(32, 16), 256, 0, stream>>>(Wvb, Xb, bv, Vto,
                                                        HIDDEN, MTOT, HIDDEN, MTOT);
  // attention -> ctx bf16 [4096][2048]
  attn_kernel<<<dim3(SEQ / BQ, BATCH * NHEADS), 256, 0, stream>>>(QKo, Vto, msk, Cb);
  // output projection -> fp32 out
  gemm_bt<false, false><<<dim3(16, 32), 256, 0, stream>>>(Cb, Wob, bo, out,
                                                          MTOT, HIDDEN, HIDDEN, HIDDEN);
}